// Round 11
// baseline (7889.247 us; speedup 1.0000x reference)
//
#include <hip/hip_runtime.h>
#include <hip/hip_cooperative_groups.h>
#include <stdint.h>

namespace cg = cooperative_groups;

#define NN 4096
#define BB 4
#define MROWS 16        // rows per block
#define TPB 1024        // 16 waves
#define REDS 17         // padded red row stride (dwords)

typedef __attribute__((ext_vector_type(8))) short bf16x8;   // 8 bf16 (4 VGPRs)
typedef __attribute__((ext_vector_type(4))) float f32x4;    // MFMA C/D

// ---------- bf16 round-to-nearest-even ----------
__device__ __forceinline__ uint32_t bf16rne(float f) {
  uint32_t u = __float_as_uint(f);
  return (u + 0x7FFFu + ((u >> 16) & 1u)) >> 16;
}

// ---------- pack B fp32 -> two row-major bf16 planes (32 MB each) ----------
__global__ void pack_planes(const float* __restrict__ Br, const float* __restrict__ Bi,
                            uint4* __restrict__ Brb, uint4* __restrict__ Bib) {
  int i = blockIdx.x * blockDim.x + threadIdx.x;     // over N*N/8
  const float4* r4 = reinterpret_cast<const float4*>(Br) + (size_t)i * 2;
  const float4* m4 = reinterpret_cast<const float4*>(Bi) + (size_t)i * 2;
  float4 a0 = r4[0], a1 = r4[1];
  float4 b0 = m4[0], b1 = m4[1];
  uint4 o;
  o.x = bf16rne(a0.x) | (bf16rne(a0.y) << 16);
  o.y = bf16rne(a0.z) | (bf16rne(a0.w) << 16);
  o.z = bf16rne(a1.x) | (bf16rne(a1.y) << 16);
  o.w = bf16rne(a1.z) | (bf16rne(a1.w) << 16);
  Brb[i] = o;
  o.x = bf16rne(b0.x) | (bf16rne(b0.y) << 16);
  o.y = bf16rne(b0.z) | (bf16rne(b0.w) << 16);
  o.z = bf16rne(b1.x) | (bf16rne(b1.y) << 16);
  o.w = bf16rne(b1.z) | (bf16rne(b1.w) << 16);
  Bib[i] = o;
}

// ============================================================================
// Persistent cooperative kernel: all 255 steps in one launch.
// B bf16 fragments live in REGISTERS for the whole kernel (loaded once).
// x state: global bf16 plane buffers (2 x 64 KB, double-buffered), layout
// IDENTICAL to the LDS X layout so staging is a coalesced identity copy:
//   slot(nc, p) = nc*8 + ((p + rot(nc)) & 7), rot(nc) = (nc + (nc>>1)) & 7
//   (nc = node>>3, p = plane 0..7 = 4 batches x {re,im}; 16 B per slot)
// Diagonal fp32 chain: thread-resident register myval (tid<128), partner via
// __shfl_xor(.,1). One grid.sync per step. Fragment maps = round-10 verified.
// ============================================================================
__global__ __launch_bounds__(TPB)
void rnn_persistent(const uint16_t* __restrict__ Brb,
                    const uint16_t* __restrict__ Bib,
                    const float* __restrict__ omega,
                    const float* __restrict__ ang,
                    uint16_t* __restrict__ xbuf,   // 2 * 32768 bf16
                    float* __restrict__ out,
                    int NT) {
  extern __shared__ char smem[];
  char*  XB  = smem;                               // 64 KB
  float* red = (float*)(smem + 65536);             // 16 waves * 16 * REDS

  const int tid  = threadIdx.x;
  const int w    = tid >> 6;
  const int lane = tid & 63;
  const int al   = lane & 15;
  const int kq   = lane >> 4;
  const int row0 = blockIdx.x * MROWS;

  // ---- load B fragments into registers (once) ----
  const uint16_t* arow = Brb + (size_t)(row0 + al) * NN + w * 256 + kq * 8;
  const uint16_t* brow = Bib + (size_t)(row0 + al) * NN + w * 256 + kq * 8;
  bf16x8 aR0 = *(const bf16x8*)(arow +   0), aI0 = *(const bf16x8*)(brow +   0);
  bf16x8 aR1 = *(const bf16x8*)(arow +  32), aI1 = *(const bf16x8*)(brow +  32);
  bf16x8 aR2 = *(const bf16x8*)(arow +  64), aI2 = *(const bf16x8*)(brow +  64);
  bf16x8 aR3 = *(const bf16x8*)(arow +  96), aI3 = *(const bf16x8*)(brow +  96);
  bf16x8 aR4 = *(const bf16x8*)(arow + 128), aI4 = *(const bf16x8*)(brow + 128);
  bf16x8 aR5 = *(const bf16x8*)(arow + 160), aI5 = *(const bf16x8*)(brow + 160);
  bf16x8 aR6 = *(const bf16x8*)(arow + 192), aI6 = *(const bf16x8*)(brow + 192);
  bf16x8 aR7 = *(const bf16x8*)(arow + 224), aI7 = *(const bf16x8*)(brow + 224);

  const int p1 = al & 7;
  const int p2 = p1 ^ 1;
  const uint32_t sm = (al & 1) ? 0u : 0x80008000u;  // negate -xi for even cols

  // ---- t = 0: x0 = exp(i*theta); diag registers; out[0]; plane buf 0 ----
  float myval = 0.f, om = 0.f;
  int bb = 0, mm = 0, ri = 0;
  if (tid < 128) {
    int r = tid >> 3, c = tid & 7;
    mm = row0 + r; bb = c >> 1; ri = c & 1;
    om = omega[bb * NN + mm];
    float sv, cv;
    sincosf(ang[bb * NN + mm], &sv, &cv);
    myval = ri ? sv : cv;
    if (ri == 0) out[bb * NN + mm] = myval;
    int nc = mm >> 3, e = mm & 7;
    int rot = (nc + (nc >> 1)) & 7;
    xbuf[(size_t)(nc * 8 + ((c + rot) & 7)) * 8 + e] = (uint16_t)bf16rne(myval);
  }

  cg::grid_group grid = cg::this_grid();

  for (int t = 1; t < NT; ++t) {
    grid.sync();                                   // prev-step writes visible

    // ---- stage x planes: coalesced identity copy, 64 B/thread ----
    {
      const uint4* g = (const uint4*)(xbuf + (size_t)((t - 1) & 1) * 32768);
      uint4* d = (uint4*)XB;
#pragma unroll
      for (int k = 0; k < 4; ++k) d[tid + k * TPB] = g[tid + k * TPB];
    }
    __syncthreads();

    // ---- 16 MFMAs from register A-operands ----
    f32x4 accA = {0.f, 0.f, 0.f, 0.f};
    f32x4 accB = {0.f, 0.f, 0.f, 0.f};
#define SSTEP(S, AR, AI)                                                        \
    { const int nq = w * 32 + S * 4 + kq;                                       \
      const int rot = (nq + (nq >> 1)) & 7;                                     \
      bf16x8 x1 = *(const bf16x8*)(XB + (size_t)(nq * 8 + ((p1 + rot) & 7)) * 16); \
      accA = __builtin_amdgcn_mfma_f32_16x16x32_bf16(AR, x1, accA, 0, 0, 0);    \
      uint4 u2 = *(const uint4*)(XB + (size_t)(nq * 8 + ((p2 + rot) & 7)) * 16);   \
      u2.x ^= sm; u2.y ^= sm; u2.z ^= sm; u2.w ^= sm;                           \
      bf16x8 x2 = __builtin_bit_cast(bf16x8, u2);                               \
      accB = __builtin_amdgcn_mfma_f32_16x16x32_bf16(AI, x2, accB, 0, 0, 0); }
    SSTEP(0, aR0, aI0) SSTEP(1, aR1, aI1) SSTEP(2, aR2, aI2) SSTEP(3, aR3, aI3)
    SSTEP(4, aR4, aI4) SSTEP(5, aR5, aI5) SSTEP(6, aR6, aI6) SSTEP(7, aR7, aI7)
#undef SSTEP

    // ---- partial tiles -> padded LDS ----
    {
      float* rw = red + w * 16 * REDS;
      rw[(kq * 4 + 0) * REDS + al] = accA[0] + accB[0];
      rw[(kq * 4 + 1) * REDS + al] = accA[1] + accB[1];
      rw[(kq * 4 + 2) * REDS + al] = accA[2] + accB[2];
      rw[(kq * 4 + 3) * REDS + al] = accA[3] + accB[3];
    }
    __syncthreads();

    // ---- cross-wave sum + diagonal + writes ----
    if (tid < 128) {
      int r = tid >> 3, c = tid & 7;
      float s = 0.f;
#pragma unroll
      for (int w2 = 0; w2 < 16; ++w2) s += red[w2 * 16 * REDS + r * REDS + c];
      float other = __shfl_xor(myval, 1, 64);
      float xr = ri ? other : myval;
      float xi = ri ? myval : other;
      // i*omega*(xr + i*xi) = -omega*xi + i*omega*xr
      s += ri ? (om * xr) : (-om * xi);
      myval = s;                                   // fp32 diag chain stays in reg
      if (ri == 0) out[(size_t)t * (BB * NN) + bb * NN + mm] = s;
      uint16_t* dst = xbuf + (size_t)(t & 1) * 32768;
      int nc = mm >> 3, e = mm & 7;
      int rot = (nc + (nc >> 1)) & 7;
      dst[(size_t)(nc * 8 + ((c + rot) & 7)) * 8 + e] = (uint16_t)bf16rne(s);
    }
  }
}

// ============================================================================
// Fallback (fp32 B direct, per-step launches) — only if ws too small.
// ============================================================================
__global__ void init_kernel(const float* __restrict__ ang,
                            float2* __restrict__ st0, float* __restrict__ out0) {
  int i = blockIdx.x * blockDim.x + threadIdx.x;
  if (i < BB * NN) {
    float s, c;
    sincosf(ang[i], &s, &c);
    st0[i] = make_float2(c, s);
    out0[i] = c;
  }
}

__global__ __launch_bounds__(TPB)
void step_fb(const float* __restrict__ Brf, const float* __restrict__ Bif,
             const float* __restrict__ omega,
             const float2* __restrict__ stPrev, float2* __restrict__ stNext,
             float* __restrict__ outRe) {
  extern __shared__ float lds[];
  float* xl  = lds;
  float* xh  = lds + NN * 4;
  float* red = lds + NN * 8;
  const int tid = threadIdx.x;
#pragma unroll
  for (int k = 0; k < 8; ++k) {
    int idx = tid + k * TPB;
    int half = idx >> 12;
    int n = idx & (NN - 1);
    float2 v0 = stPrev[(half * 2) * NN + n];
    float2 v1 = stPrev[(half * 2 + 1) * NN + n];
    reinterpret_cast<float4*>(half ? xh : xl)[n] = make_float4(v0.x, v0.y, v1.x, v1.y);
  }
  __syncthreads();
  const int w = tid >> 6, lane = tid & 63, rg = w >> 2, q = w & 3;
  const int row0 = blockIdx.x * MROWS + rg * 4;
  float acc[4][8];
#pragma unroll
  for (int r = 0; r < 4; ++r)
#pragma unroll
    for (int c = 0; c < 8; ++c) acc[r][c] = 0.0f;
#define CFMA(A, BR, BI, XA, XB)                                   \
  A[0] = fmaf(BR, XA.x, A[0]); A[0] = fmaf(-BI, XA.y, A[0]);      \
  A[1] = fmaf(BR, XA.y, A[1]); A[1] = fmaf(BI, XA.x, A[1]);       \
  A[2] = fmaf(BR, XA.z, A[2]); A[2] = fmaf(-BI, XA.w, A[2]);      \
  A[3] = fmaf(BR, XA.w, A[3]); A[3] = fmaf(BI, XA.z, A[3]);       \
  A[4] = fmaf(BR, XB.x, A[4]); A[4] = fmaf(-BI, XB.y, A[4]);      \
  A[5] = fmaf(BR, XB.y, A[5]); A[5] = fmaf(BI, XB.x, A[5]);       \
  A[6] = fmaf(BR, XB.z, A[6]); A[6] = fmaf(-BI, XB.w, A[6]);      \
  A[7] = fmaf(BR, XB.w, A[7]); A[7] = fmaf(BI, XB.z, A[7]);
  for (int i4 = 0; i4 < 4; ++i4) {
    const int n0 = q * 1024 + i4 * 256 + lane * 4;
    float4 xa[4], xb[4];
#pragma unroll
    for (int j = 0; j < 4; ++j) {
      xa[j] = reinterpret_cast<const float4*>(xl)[n0 + j];
      xb[j] = reinterpret_cast<const float4*>(xh)[n0 + j];
    }
#pragma unroll
    for (int r = 0; r < 4; ++r) {
      const float4 pvr = reinterpret_cast<const float4*>(Brf + (size_t)(row0 + r) * NN)[q * 256 + i4 * 64 + lane];
      const float4 pvi = reinterpret_cast<const float4*>(Bif + (size_t)(row0 + r) * NN)[q * 256 + i4 * 64 + lane];
      float* a = acc[r];
      CFMA(a, pvr.x, pvi.x, xa[0], xb[0]);
      CFMA(a, pvr.y, pvi.y, xa[1], xb[1]);
      CFMA(a, pvr.z, pvi.z, xa[2], xb[2]);
      CFMA(a, pvr.w, pvi.w, xa[3], xb[3]);
    }
  }
#undef CFMA
  float t0 = acc[0][0], t1 = acc[0][1], t2 = acc[0][2], t3 = acc[0][3];
  float t4 = acc[0][4], t5 = acc[0][5], t6 = acc[0][6], t7 = acc[0][7];
  float t8 = acc[1][0], t9 = acc[1][1], t10 = acc[1][2], t11 = acc[1][3];
  float t12 = acc[1][4], t13 = acc[1][5], t14 = acc[1][6], t15 = acc[1][7];
  float t16 = acc[2][0], t17 = acc[2][1], t18 = acc[2][2], t19 = acc[2][3];
  float t20 = acc[2][4], t21 = acc[2][5], t22 = acc[2][6], t23 = acc[2][7];
  float t24 = acc[3][0], t25 = acc[3][1], t26 = acc[3][2], t27 = acc[3][3];
  float t28 = acc[3][4], t29 = acc[3][5], t30 = acc[3][6], t31 = acc[3][7];
#define RSTEP(LO, HI, M)                                          \
  { float s_ = up ? LO : HI;                                      \
    s_ = __shfl_xor(s_, M, 64);                                   \
    LO = (up ? HI : LO) + s_; }
  { const bool up = (lane & 32) != 0;
    RSTEP(t0, t16, 32)  RSTEP(t1, t17, 32)  RSTEP(t2, t18, 32)  RSTEP(t3, t19, 32)
    RSTEP(t4, t20, 32)  RSTEP(t5, t21, 32)  RSTEP(t6, t22, 32)  RSTEP(t7, t23, 32)
    RSTEP(t8, t24, 32)  RSTEP(t9, t25, 32)  RSTEP(t10, t26, 32) RSTEP(t11, t27, 32)
    RSTEP(t12, t28, 32) RSTEP(t13, t29, 32) RSTEP(t14, t30, 32) RSTEP(t15, t31, 32) }
  { const bool up = (lane & 16) != 0;
    RSTEP(t0, t8, 16)  RSTEP(t1, t9, 16)  RSTEP(t2, t10, 16) RSTEP(t3, t11, 16)
    RSTEP(t4, t12, 16) RSTEP(t5, t13, 16) RSTEP(t6, t14, 16) RSTEP(t7, t15, 16) }
  { const bool up = (lane & 8) != 0;
    RSTEP(t0, t4, 8) RSTEP(t1, t5, 8) RSTEP(t2, t6, 8) RSTEP(t3, t7, 8) }
  { const bool up = (lane & 4) != 0;
    RSTEP(t0, t2, 4) RSTEP(t1, t3, 4) }
  { const bool up = (lane & 2) != 0;
    RSTEP(t0, t1, 2) }
#undef RSTEP
  t0 += __shfl_xor(t0, 1, 64);
  if (!(lane & 1)) red[w * 32 + ((lane >> 1) & 31)] = t0;
  __syncthreads();
  if (tid < 128) {
    int rg2 = tid >> 5, v = tid & 31;
    float s = red[(rg2 * 4 + 0) * 32 + v] + red[(rg2 * 4 + 1) * 32 + v] +
              red[(rg2 * 4 + 2) * 32 + v] + red[(rg2 * 4 + 3) * 32 + v];
    int r = v >> 3, c = v & 7, b = c >> 1, ri = c & 1;
    int m = blockIdx.x * MROWS + rg2 * 4 + r;
    float om = omega[b * NN + m];
    const float* xs = (b < 2) ? xl : xh;
    float xr = xs[m * 4 + (b & 1) * 2];
    float xi = xs[m * 4 + (b & 1) * 2 + 1];
    s += (ri == 0) ? (-om * xi) : (om * xr);
    reinterpret_cast<float*>(stNext)[(b * NN + m) * 2 + ri] = s;
    if (ri == 0) outRe[b * NN + m] = s;
  }
}

// ---------- host ----------
extern "C" void kernel_launch(void* const* d_in, const int* in_sizes, int n_in,
                              void* d_out, int out_size, void* d_ws, size_t ws_size,
                              hipStream_t stream) {
  const float* B_real = (const float*)d_in[0];
  const float* B_imag = (const float*)d_in[1];
  const float* omega  = (const float*)d_in[2];
  const float* ang    = (const float*)d_in[3];
  float* out = (float*)d_out;

  int NT = out_size / (BB * NN);                                 // 256
  const size_t planeBytes = (size_t)NN * NN * 2;                 // 32 MB bf16 plane
  const size_t xbufBytes  = (size_t)2 * 8 * NN * 2;              // 128 KB
  const bool coop = ws_size >= 2 * planeBytes + xbufBytes;

  if (coop) {
    uint16_t* Brb = (uint16_t*)d_ws;
    uint16_t* Bib = Brb + (size_t)NN * NN;
    uint16_t* xbuf = (uint16_t*)((char*)d_ws + 2 * planeBytes);

    const size_t shmem = 65536 + (size_t)16 * 16 * REDS * 4;     // 82944 B
    (void)hipFuncSetAttribute((const void*)&rnn_persistent,
                              hipFuncAttributeMaxDynamicSharedMemorySize, (int)shmem);

    pack_planes<<<NN * NN / 8 / 256, 256, 0, stream>>>(B_real, B_imag,
                                                       (uint4*)Brb, (uint4*)Bib);

    void* kargs[7];
    kargs[0] = (void*)&Brb;
    kargs[1] = (void*)&Bib;
    kargs[2] = (void*)&omega;
    kargs[3] = (void*)&ang;
    kargs[4] = (void*)&xbuf;
    kargs[5] = (void*)&out;
    kargs[6] = (void*)&NT;
    (void)hipLaunchCooperativeKernel((const void*)&rnn_persistent,
                                     dim3(NN / MROWS), dim3(TPB),
                                     kargs, (unsigned int)shmem, stream);
  } else {
    // fallback: per-step launches, fp32 B from inputs, state ping-pong in ws
    float2* st0 = (float2*)d_ws;
    float2* st1 = st0 + BB * NN;
    const size_t shmemF = (size_t)(NN * 8 + 16 * 32) * sizeof(float);
    (void)hipFuncSetAttribute((const void*)&step_fb,
                              hipFuncAttributeMaxDynamicSharedMemorySize, (int)shmemF);
    init_kernel<<<(BB * NN + 255) / 256, 256, 0, stream>>>(ang, st0, out);
    for (int t = 1; t < NT; ++t) {
      float2* sp = ((t - 1) & 1) ? st1 : st0;
      float2* sn = (t & 1) ? st1 : st0;
      float* outT = out + (size_t)t * BB * NN;
      step_fb<<<NN / MROWS, TPB, shmemF, stream>>>(B_real, B_imag, omega, sp, sn, outT);
    }
  }
}

// Round 12
// 4169.844 us; speedup vs baseline: 1.8920x; 1.8920x over previous
//
#include <hip/hip_runtime.h>
#include <stdint.h>

#define NN 4096
#define BB 4
#define MROWS 16        // rows per block
#define TPB 1024        // 16 waves
#define NBLK 256        // grid (1 block/CU)
#define REDS 17         // padded red row stride (dwords)

typedef __attribute__((ext_vector_type(8))) short bf16x8;   // 8 bf16 (4 VGPRs)
typedef __attribute__((ext_vector_type(4))) float f32x4;    // MFMA C/D

// ---------- bf16 round-to-nearest-even ----------
__device__ __forceinline__ uint32_t bf16rne(float f) {
  uint32_t u = __float_as_uint(f);
  return (u + 0x7FFFu + ((u >> 16) & 1u)) >> 16;
}

// ---------- pack B fp32 -> two row-major bf16 planes (32 MB each) ----------
__global__ void pack_planes(const float* __restrict__ Br, const float* __restrict__ Bi,
                            uint4* __restrict__ Brb, uint4* __restrict__ Bib) {
  int i = blockIdx.x * blockDim.x + threadIdx.x;     // over N*N/8
  const float4* r4 = reinterpret_cast<const float4*>(Br) + (size_t)i * 2;
  const float4* m4 = reinterpret_cast<const float4*>(Bi) + (size_t)i * 2;
  float4 a0 = r4[0], a1 = r4[1];
  float4 b0 = m4[0], b1 = m4[1];
  uint4 o;
  o.x = bf16rne(a0.x) | (bf16rne(a0.y) << 16);
  o.y = bf16rne(a0.z) | (bf16rne(a0.w) << 16);
  o.z = bf16rne(a1.x) | (bf16rne(a1.y) << 16);
  o.w = bf16rne(a1.z) | (bf16rne(a1.w) << 16);
  Brb[i] = o;
  o.x = bf16rne(b0.x) | (bf16rne(b0.y) << 16);
  o.y = bf16rne(b0.z) | (bf16rne(b0.w) << 16);
  o.z = bf16rne(b1.x) | (bf16rne(b1.y) << 16);
  o.w = bf16rne(b1.z) | (bf16rne(b1.w) << 16);
  Bib[i] = o;
}

// ---------- lightweight grid barrier (release/acquire on cnt[idx]) ----------
__device__ __forceinline__ void gbar(uint32_t* cnt, int idx) {
  __syncthreads();                     // drains every wave's stores (vmcnt0 + s_barrier)
  if (threadIdx.x == 0) {
    __hip_atomic_fetch_add(&cnt[idx], 1u, __ATOMIC_RELEASE, __HIP_MEMORY_SCOPE_AGENT);
    while (__hip_atomic_load(&cnt[idx], __ATOMIC_RELAXED, __HIP_MEMORY_SCOPE_AGENT) < NBLK) {}
    (void)__hip_atomic_load(&cnt[idx], __ATOMIC_ACQUIRE, __HIP_MEMORY_SCOPE_AGENT);
  }
  __syncthreads();
}

// ============================================================================
// Persistent kernel: all steps in one launch; B bf16 fragments in VGPRs.
// x state: flat bf16 planes xbuf[buf][plane c=2b+ri][node n], double-buffered.
// Waves read only their own k-slice -> direct global->reg x loads (no LDS stage).
// Fragment maps identical to round-10/11 (verified, absmax 0.0039):
//   A: lane l holds A[row=l&15][k=(l>>4)*8+j];  B-op: B[k=(l>>4)*8+j][col=l&15]
//   C/D: lane l holds D[row=(l>>4)*4+i][col=l&15]; cols 8..15 garbage (discarded)
// ============================================================================
__global__ __launch_bounds__(TPB, 4)   // 4 waves/SIMD -> 128-VGPR cap: keep B resident
void rnn_persistent(const uint16_t* __restrict__ Brb,
                    const uint16_t* __restrict__ Bib,
                    const float* __restrict__ omega,
                    const float* __restrict__ ang,
                    uint16_t* __restrict__ xbuf,   // 2 * 8*NN bf16
                    uint32_t* __restrict__ cnt,    // NBLK-counting barrier slots
                    float* __restrict__ out,
                    int NT) {
  __shared__ float red[16 * 16 * REDS];            // 17408 B

  const int tid  = threadIdx.x;
  const int w    = tid >> 6;
  const int lane = tid & 63;
  const int al   = lane & 15;
  const int kq   = lane >> 4;
  const int row0 = blockIdx.x * MROWS;
  const int p1   = al & 7;
  const int p2   = p1 ^ 1;
  const uint64_t sm64 = (al & 1) ? 0ull : 0x8000800080008000ull;  // negate -xi (even cols)

  // ---- load B fragments into registers (once; stay resident all 255 steps) ----
  const uint16_t* arow = Brb + (size_t)(row0 + al) * NN + w * 256 + kq * 8;
  const uint16_t* brow = Bib + (size_t)(row0 + al) * NN + w * 256 + kq * 8;
  bf16x8 aR0 = *(const bf16x8*)(arow +   0), aI0 = *(const bf16x8*)(brow +   0);
  bf16x8 aR1 = *(const bf16x8*)(arow +  32), aI1 = *(const bf16x8*)(brow +  32);
  bf16x8 aR2 = *(const bf16x8*)(arow +  64), aI2 = *(const bf16x8*)(brow +  64);
  bf16x8 aR3 = *(const bf16x8*)(arow +  96), aI3 = *(const bf16x8*)(brow +  96);
  bf16x8 aR4 = *(const bf16x8*)(arow + 128), aI4 = *(const bf16x8*)(brow + 128);
  bf16x8 aR5 = *(const bf16x8*)(arow + 160), aI5 = *(const bf16x8*)(brow + 160);
  bf16x8 aR6 = *(const bf16x8*)(arow + 192), aI6 = *(const bf16x8*)(brow + 192);
  bf16x8 aR7 = *(const bf16x8*)(arow + 224), aI7 = *(const bf16x8*)(brow + 224);

  // ---- t=0: x0 = exp(i*theta); diag regs; out[0]; xbuf buffer 0 ----
  float myval = 0.f, om = 0.f;
  int bb = 0, mm = 0, ri = 0, cc = 0;
  if (tid < 128) {
    int r = tid >> 3; cc = tid & 7;
    mm = row0 + r; bb = cc >> 1; ri = cc & 1;
    om = omega[bb * NN + mm];
    float sv, cv;
    sincosf(ang[bb * NN + mm], &sv, &cv);
    myval = ri ? sv : cv;
    if (!ri) out[bb * NN + mm] = myval;
    xbuf[cc * NN + mm] = (uint16_t)bf16rne(myval);
  }
  gbar(cnt, 0);

  const int nb = w * 256 + kq * 8;                 // this lane's k-window base

  for (int t = 1; t < NT; ++t) {
    const uint16_t* xs = xbuf + (size_t)((t - 1) & 1) * (8 * NN);
    f32x4 accA = {0.f, 0.f, 0.f, 0.f};
    f32x4 accB = {0.f, 0.f, 0.f, 0.f};

#define SSTEP(S, AR, AI)                                                        \
    { const uint16_t* x1p = xs + p1 * NN + nb + S * 32;                         \
      const uint16_t* x2p = xs + p2 * NN + nb + S * 32;                         \
      union { uint64_t q[2]; bf16x8 v; } u1, u2;                                \
      u1.q[0] = *(const uint64_t*)(x1p);                                        \
      u1.q[1] = *(const uint64_t*)(x1p + 4);                                    \
      u2.q[0] = *(const uint64_t*)(x2p) ^ sm64;                                 \
      u2.q[1] = *(const uint64_t*)(x2p + 4) ^ sm64;                             \
      accA = __builtin_amdgcn_mfma_f32_16x16x32_bf16(AR, u1.v, accA, 0, 0, 0);  \
      accB = __builtin_amdgcn_mfma_f32_16x16x32_bf16(AI, u2.v, accB, 0, 0, 0); }
    SSTEP(0, aR0, aI0) SSTEP(1, aR1, aI1) SSTEP(2, aR2, aI2) SSTEP(3, aR3, aI3)
    SSTEP(4, aR4, aI4) SSTEP(5, aR5, aI5) SSTEP(6, aR6, aI6) SSTEP(7, aR7, aI7)
#undef SSTEP

    // ---- partial tiles -> padded LDS ----
    {
      float* rw = red + w * 16 * REDS;
      rw[(kq * 4 + 0) * REDS + al] = accA[0] + accB[0];
      rw[(kq * 4 + 1) * REDS + al] = accA[1] + accB[1];
      rw[(kq * 4 + 2) * REDS + al] = accA[2] + accB[2];
      rw[(kq * 4 + 3) * REDS + al] = accA[3] + accB[3];
    }
    __syncthreads();

    // ---- cross-wave sum + diagonal + writes ----
    if (tid < 128) {
      int r = tid >> 3;
      float s = 0.f;
#pragma unroll
      for (int w2 = 0; w2 < 16; ++w2) s += red[w2 * 16 * REDS + r * REDS + cc];
      float other = __shfl_xor(myval, 1, 64);
      float xr = ri ? other : myval;
      float xi = ri ? myval : other;
      // i*omega*(xr + i*xi) = -omega*xi + i*omega*xr
      s += ri ? (om * xr) : (-om * xi);
      myval = s;                                   // fp32 diag chain stays in reg
      if (!ri) out[(size_t)t * (BB * NN) + bb * NN + mm] = s;
      xbuf[(size_t)(t & 1) * (8 * NN) + cc * NN + mm] = (uint16_t)bf16rne(s);
    }

    if (t < NT - 1) gbar(cnt, t);
  }
}

// ============================================================================
// Fallback (fp32 B direct, per-step launches) — only if coop launch fails.
// ============================================================================
__global__ void init_kernel(const float* __restrict__ ang,
                            float2* __restrict__ st0, float* __restrict__ out0) {
  int i = blockIdx.x * blockDim.x + threadIdx.x;
  if (i < BB * NN) {
    float s, c;
    sincosf(ang[i], &s, &c);
    st0[i] = make_float2(c, s);
    out0[i] = c;
  }
}

__global__ __launch_bounds__(TPB)
void step_fb(const float* __restrict__ Brf, const float* __restrict__ Bif,
             const float* __restrict__ omega,
             const float2* __restrict__ stPrev, float2* __restrict__ stNext,
             float* __restrict__ outRe) {
  extern __shared__ float lds[];
  float* xl  = lds;
  float* xh  = lds + NN * 4;
  float* red = lds + NN * 8;
  const int tid = threadIdx.x;
#pragma unroll
  for (int k = 0; k < 8; ++k) {
    int idx = tid + k * TPB;
    int half = idx >> 12;
    int n = idx & (NN - 1);
    float2 v0 = stPrev[(half * 2) * NN + n];
    float2 v1 = stPrev[(half * 2 + 1) * NN + n];
    reinterpret_cast<float4*>(half ? xh : xl)[n] = make_float4(v0.x, v0.y, v1.x, v1.y);
  }
  __syncthreads();
  const int w = tid >> 6, lane = tid & 63, rg = w >> 2, q = w & 3;
  const int row0 = blockIdx.x * MROWS + rg * 4;
  float acc[4][8];
#pragma unroll
  for (int r = 0; r < 4; ++r)
#pragma unroll
    for (int c = 0; c < 8; ++c) acc[r][c] = 0.0f;
#define CFMA(A, BR, BI, XA, XB)                                   \
  A[0] = fmaf(BR, XA.x, A[0]); A[0] = fmaf(-BI, XA.y, A[0]);      \
  A[1] = fmaf(BR, XA.y, A[1]); A[1] = fmaf(BI, XA.x, A[1]);       \
  A[2] = fmaf(BR, XA.z, A[2]); A[2] = fmaf(-BI, XA.w, A[2]);      \
  A[3] = fmaf(BR, XA.w, A[3]); A[3] = fmaf(BI, XA.z, A[3]);       \
  A[4] = fmaf(BR, XB.x, A[4]); A[4] = fmaf(-BI, XB.y, A[4]);      \
  A[5] = fmaf(BR, XB.y, A[5]); A[5] = fmaf(BI, XB.x, A[5]);       \
  A[6] = fmaf(BR, XB.z, A[6]); A[6] = fmaf(-BI, XB.w, A[6]);      \
  A[7] = fmaf(BR, XB.w, A[7]); A[7] = fmaf(BI, XB.z, A[7]);
  for (int i4 = 0; i4 < 4; ++i4) {
    const int n0 = q * 1024 + i4 * 256 + lane * 4;
    float4 xa[4], xb[4];
#pragma unroll
    for (int j = 0; j < 4; ++j) {
      xa[j] = reinterpret_cast<const float4*>(xl)[n0 + j];
      xb[j] = reinterpret_cast<const float4*>(xh)[n0 + j];
    }
#pragma unroll
    for (int r = 0; r < 4; ++r) {
      const float4 pvr = reinterpret_cast<const float4*>(Brf + (size_t)(row0 + r) * NN)[q * 256 + i4 * 64 + lane];
      const float4 pvi = reinterpret_cast<const float4*>(Bif + (size_t)(row0 + r) * NN)[q * 256 + i4 * 64 + lane];
      float* a = acc[r];
      CFMA(a, pvr.x, pvi.x, xa[0], xb[0]);
      CFMA(a, pvr.y, pvi.y, xa[1], xb[1]);
      CFMA(a, pvr.z, pvi.z, xa[2], xb[2]);
      CFMA(a, pvr.w, pvi.w, xa[3], xb[3]);
    }
  }
#undef CFMA
  float t0 = acc[0][0], t1 = acc[0][1], t2 = acc[0][2], t3 = acc[0][3];
  float t4 = acc[0][4], t5 = acc[0][5], t6 = acc[0][6], t7 = acc[0][7];
  float t8 = acc[1][0], t9 = acc[1][1], t10 = acc[1][2], t11 = acc[1][3];
  float t12 = acc[1][4], t13 = acc[1][5], t14 = acc[1][6], t15 = acc[1][7];
  float t16 = acc[2][0], t17 = acc[2][1], t18 = acc[2][2], t19 = acc[2][3];
  float t20 = acc[2][4], t21 = acc[2][5], t22 = acc[2][6], t23 = acc[2][7];
  float t24 = acc[3][0], t25 = acc[3][1], t26 = acc[3][2], t27 = acc[3][3];
  float t28 = acc[3][4], t29 = acc[3][5], t30 = acc[3][6], t31 = acc[3][7];
#define RSTEP(LO, HI, M)                                          \
  { float s_ = up ? LO : HI;                                      \
    s_ = __shfl_xor(s_, M, 64);                                   \
    LO = (up ? HI : LO) + s_; }
  { const bool up = (lane & 32) != 0;
    RSTEP(t0, t16, 32)  RSTEP(t1, t17, 32)  RSTEP(t2, t18, 32)  RSTEP(t3, t19, 32)
    RSTEP(t4, t20, 32)  RSTEP(t5, t21, 32)  RSTEP(t6, t22, 32)  RSTEP(t7, t23, 32)
    RSTEP(t8, t24, 32)  RSTEP(t9, t25, 32)  RSTEP(t10, t26, 32) RSTEP(t11, t27, 32)
    RSTEP(t12, t28, 32) RSTEP(t13, t29, 32) RSTEP(t14, t30, 32) RSTEP(t15, t31, 32) }
  { const bool up = (lane & 16) != 0;
    RSTEP(t0, t8, 16)  RSTEP(t1, t9, 16)  RSTEP(t2, t10, 16) RSTEP(t3, t11, 16)
    RSTEP(t4, t12, 16) RSTEP(t5, t13, 16) RSTEP(t6, t14, 16) RSTEP(t7, t15, 16) }
  { const bool up = (lane & 8) != 0;
    RSTEP(t0, t4, 8) RSTEP(t1, t5, 8) RSTEP(t2, t6, 8) RSTEP(t3, t7, 8) }
  { const bool up = (lane & 4) != 0;
    RSTEP(t0, t2, 4) RSTEP(t1, t3, 4) }
  { const bool up = (lane & 2) != 0;
    RSTEP(t0, t1, 2) }
#undef RSTEP
  t0 += __shfl_xor(t0, 1, 64);
  if (!(lane & 1)) red[w * 32 + ((lane >> 1) & 31)] = t0;
  __syncthreads();
  if (tid < 128) {
    int rg2 = tid >> 5, v = tid & 31;
    float s = red[(rg2 * 4 + 0) * 32 + v] + red[(rg2 * 4 + 1) * 32 + v] +
              red[(rg2 * 4 + 2) * 32 + v] + red[(rg2 * 4 + 3) * 32 + v];
    int r = v >> 3, c = v & 7, b = c >> 1, ri = c & 1;
    int m = blockIdx.x * MROWS + rg2 * 4 + r;
    float om = omega[b * NN + m];
    const float* xs = (b < 2) ? xl : xh;
    float xr = xs[m * 4 + (b & 1) * 2];
    float xi = xs[m * 4 + (b & 1) * 2 + 1];
    s += (ri == 0) ? (-om * xi) : (om * xr);
    reinterpret_cast<float*>(stNext)[(b * NN + m) * 2 + ri] = s;
    if (ri == 0) outRe[b * NN + m] = s;
  }
}

// ---------- host ----------
extern "C" void kernel_launch(void* const* d_in, const int* in_sizes, int n_in,
                              void* d_out, int out_size, void* d_ws, size_t ws_size,
                              hipStream_t stream) {
  const float* B_real = (const float*)d_in[0];
  const float* B_imag = (const float*)d_in[1];
  const float* omega  = (const float*)d_in[2];
  const float* ang    = (const float*)d_in[3];
  float* out = (float*)d_out;

  int NT = out_size / (BB * NN);                                 // 256
  const size_t planeBytes = (size_t)NN * NN * 2;                 // 32 MB
  const size_t xbufBytes  = (size_t)2 * 8 * NN * 2;              // 128 KB
  const size_t cntBytes   = (size_t)NBLK * sizeof(uint32_t);     // 1 KB (>= NT slots)
  const bool coop = ws_size >= 2 * planeBytes + xbufBytes + cntBytes;

  hipError_t launched = hipErrorUnknown;
  if (coop) {
    uint16_t* Brb = (uint16_t*)d_ws;
    uint16_t* Bib = Brb + (size_t)NN * NN;
    uint16_t* xbuf = (uint16_t*)((char*)d_ws + 2 * planeBytes);
    uint32_t* cnt  = (uint32_t*)((char*)d_ws + 2 * planeBytes + xbufBytes);

    (void)hipMemsetAsync((void*)cnt, 0, cntBytes, stream);       // barrier slots -> 0
    pack_planes<<<NN * NN / 8 / 256, 256, 0, stream>>>(B_real, B_imag,
                                                       (uint4*)Brb, (uint4*)Bib);

    void* kargs[8];
    kargs[0] = (void*)&Brb;
    kargs[1] = (void*)&Bib;
    kargs[2] = (void*)&omega;
    kargs[3] = (void*)&ang;
    kargs[4] = (void*)&xbuf;
    kargs[5] = (void*)&cnt;
    kargs[6] = (void*)&out;
    kargs[7] = (void*)&NT;
    launched = hipLaunchCooperativeKernel((const void*)&rnn_persistent,
                                          dim3(NBLK), dim3(TPB),
                                          kargs, 0, stream);
  }

  if (launched != hipSuccess) {
    // fallback: per-step launches, fp32 B from inputs, state ping-pong in ws
    float2* st0 = (float2*)d_ws;
    float2* st1 = st0 + BB * NN;
    const size_t shmemF = (size_t)(NN * 8 + 16 * 32) * sizeof(float);
    (void)hipFuncSetAttribute((const void*)&step_fb,
                              hipFuncAttributeMaxDynamicSharedMemorySize, (int)shmemF);
    init_kernel<<<(BB * NN + 255) / 256, 256, 0, stream>>>(ang, st0, out);
    for (int t = 1; t < NT; ++t) {
      float2* sp = ((t - 1) & 1) ? st1 : st0;
      float2* sn = (t & 1) ? st1 : st0;
      float* outT = out + (size_t)t * BB * NN;
      step_fb<<<NN / MROWS, TPB, shmemF, stream>>>(B_real, B_imag, omega, sp, sn, outT);
    }
  }
}